// Round 9
// baseline (282.429 us; speedup 1.0000x reference)
//
#include <hip/hip_runtime.h>

#define BSH 9              // 512 nodes per dst bucket
#define BNODES 512
#define NBLK_A 256         // blocks in hist/place passes

typedef __attribute__((ext_vector_type(8))) short short8;
typedef __attribute__((ext_vector_type(4))) float floatx4;

static __device__ inline float bf2f(unsigned short u) {
    union { unsigned int i; float f; } v; v.i = ((unsigned int)u) << 16; return v.f;
}
static __device__ inline unsigned f2bf(float f) {
    union { float f; unsigned int i; } v; v.f = f;
    unsigned int x = v.i;
    return (x + 0x7FFF + ((x >> 16) & 1)) >> 16;  // RNE
}
static __device__ inline float asf(unsigned int u) {
    union { unsigned int i; float f; } v; v.i = u; return v.f;
}
static __device__ inline unsigned asu(float f) {
    union { float f; unsigned int i; } v; v.f = f; return v.i;
}

// ---------------------------------------------------------------------------
// K1: tables. msg1t[(r*64+combo)][64] bf16 (= x1 @ W1_r), root1t[64][64] f32
// ---------------------------------------------------------------------------
__global__ void build_tables(const float* __restrict__ pre_w, const float* __restrict__ pre_b,
                             const float* __restrict__ w1, const float* __restrict__ root1,
                             const float* __restrict__ b1,
                             unsigned short* __restrict__ msg1t, float* __restrict__ root1t) {
    int combo = blockIdx.x, j = threadIdx.x;
    __shared__ float x1s[32];
    int s = combo >> 3, c = combo & 7;
    if (j < 32) {
        float v = pre_w[s * 32 + j] + pre_w[(8 + c) * 32 + j] + pre_b[j];
        x1s[j] = v > 0.f ? v : 0.f;
    }
    __syncthreads();
    float acc = b1[j];
#pragma unroll
    for (int k = 0; k < 32; ++k) acc = fmaf(x1s[k], root1[k * 64 + j], acc);
    root1t[combo * 64 + j] = acc;
    for (int r = 0; r < 3; ++r) {
        float a = 0.f;
#pragma unroll
        for (int k = 0; k < 32; ++k) a = fmaf(x1s[k], w1[(r * 32 + k) * 64 + j], a);
        msg1t[((r << 6) | combo) * 64 + j] = (unsigned short)f2bf(a);
    }
}

// ---------------------------------------------------------------------------
// K2: B-fragments for the [64,256] matrix [root2 | W2_0 | W2_1 | W2_2].
//   B2f[((nt*2+kt)*64+l)*8+i] = B[kt*32+(l>>4)*8+i][nt*16+(l&15)]
// ---------------------------------------------------------------------------
__global__ void prep_B2(const float* __restrict__ root2, const float* __restrict__ w2,
                        unsigned short* __restrict__ B2f) {
    int t = blockIdx.x * blockDim.x + threadIdx.x;
    if (t >= 16 * 2 * 64 * 8) return;
    int i = t & 7, l = (t >> 3) & 63, kt = (t >> 9) & 1, nt = t >> 10;
    int k = kt * 32 + ((l >> 4) * 8) + i;
    int col = nt * 16 + (l & 15);
    float v;
    if (col < 64) v = root2[k * 64 + col];
    else {
        int r = (col - 64) >> 6, wcol = (col - 64) & 63;
        v = w2[(r * 64 + k) * 64 + wcol];
    }
    B2f[t] = (unsigned short)f2bf(v);
}

// K3: combo[i] as u8
__global__ void combo_kernel(const int* __restrict__ node_x, unsigned char* __restrict__ combo, int N) {
    int i = blockIdx.x * blockDim.x + threadIdx.x;
    if (i < N) combo[i] = (unsigned char)(node_x[2 * i] * 8 + node_x[2 * i + 1]);
}

// ---------------------------------------------------------------------------
// K4 (pass A0): per-block dst-bucket histogram. hist[b*NBLK_A + blk]
// ---------------------------------------------------------------------------
__global__ void __launch_bounds__(256) hist_kernel(const int* __restrict__ ei,
                                                   int* __restrict__ hist, int E, int NB, int chunk) {
    __shared__ int lh[256];
    for (int t = threadIdx.x; t < NB; t += 256) lh[t] = 0;
    __syncthreads();
    int s = blockIdx.x * chunk, e1 = min(E, s + chunk);
    for (int e = s + threadIdx.x; e < e1; e += 256)
        atomicAdd(&lh[ei[E + e] >> BSH], 1);
    __syncthreads();
    for (int b = threadIdx.x; b < NB; b += 256) hist[b * NBLK_A + blockIdx.x] = lh[b];
}

// generic exclusive scan (3 kernels)
__global__ void scan1(const int* __restrict__ in, int* __restrict__ out,
                      int* __restrict__ bsums, int n) {
    __shared__ int s[1024];
    int i = blockIdx.x * 1024 + threadIdx.x;
    int d = (i < n) ? in[i] : 0;
    s[threadIdx.x] = d;
    __syncthreads();
    for (int off = 1; off < 1024; off <<= 1) {
        int v = (threadIdx.x >= off) ? s[threadIdx.x - off] : 0;
        __syncthreads();
        s[threadIdx.x] += v;
        __syncthreads();
    }
    if (i < n) out[i] = s[threadIdx.x] - d;
    if (threadIdx.x == 1023) bsums[blockIdx.x] = s[1023];
}
__global__ void scan2(int* __restrict__ bsums, int nb) {
    __shared__ int s[128];
    int v = (threadIdx.x < nb) ? bsums[threadIdx.x] : 0;
    s[threadIdx.x] = v;
    __syncthreads();
    for (int off = 1; off < 128; off <<= 1) {
        int u = (threadIdx.x >= off) ? s[threadIdx.x - off] : 0;
        __syncthreads();
        s[threadIdx.x] += u;
        __syncthreads();
    }
    if (threadIdx.x < nb) bsums[threadIdx.x] = s[threadIdx.x] - v;
}
__global__ void scan3(int* __restrict__ out, const int* __restrict__ bsums, int n) {
    int i = blockIdx.x * 1024 + threadIdx.x;
    if (i < n) out[i] += bsums[blockIdx.x];
}

// ---------------------------------------------------------------------------
// K5 (pass A1): place edges into dst-buckets. staged = dloc<<19 | rel<<17 | src
// ---------------------------------------------------------------------------
__global__ void __launch_bounds__(256) place_kernel(const int* __restrict__ ei, const int* __restrict__ et,
                                                    const int* __restrict__ off, unsigned* __restrict__ staged,
                                                    int E, int NB, int chunk) {
    __shared__ int lh[256];
    for (int t = threadIdx.x; t < NB; t += 256) lh[t] = 0;
    __syncthreads();
    int s = blockIdx.x * chunk, e1 = min(E, s + chunk);
    for (int e = s + threadIdx.x; e < e1; e += 256) {
        int d = ei[E + e];
        int b = d >> BSH;
        int lr = atomicAdd(&lh[b], 1);
        int pos = off[b * NBLK_A + blockIdx.x] + lr;
        staged[pos] = ((unsigned)(d & (BNODES - 1)) << 19) | ((unsigned)et[e] << 17) | (unsigned)ei[e];
    }
}

// ---------------------------------------------------------------------------
// K6 (pass B): finalize into whole-node even(x4)-padded CSR with per-edge
// precomputed weight w = 1/cnt(dst,rel). Edge order within a node arbitrary.
//   edges2[e] = { (rel*N+src)*16 (uint2 row offset into Y), asu(w) }
//   edges1[e] = f2bf(w)<<16 | rel<<6 | combo(src)      (pads: all zero)
//   base1[i], plen[i] (padded length, multiple of 4)
// Bucket capacity = raw + 3*BNODES.
// ---------------------------------------------------------------------------
__global__ void __launch_bounds__(256) finalize_kernel(
        const unsigned* __restrict__ staged, const int* __restrict__ off,
        const unsigned char* __restrict__ combo,
        unsigned* __restrict__ edges1, uint2* __restrict__ edges2,
        int* __restrict__ base1, unsigned short* __restrict__ plen,
        int E, int N, int NB) {
    __shared__ int lrel[BNODES * 3];   // per-(node,rel) counts (stay counts)
    __shared__ float lwf[BNODES * 3];  // 1/count
    __shared__ int lcnt[BNODES];       // placement cursors
    __shared__ int lbase[BNODES];
    __shared__ int part[256];
    int blk = blockIdx.x;
    int d0 = blk * BNODES;
    int nn = min(BNODES, N - d0);
    int estart = off[blk * NBLK_A];
    int eend = (blk == NB - 1) ? E : off[(blk + 1) * NBLK_A];
    int ebase = estart + blk * (BNODES * 3);   // padded-capacity base
    for (int t = threadIdx.x; t < BNODES * 3; t += 256) lrel[t] = 0;
    __syncthreads();
    for (int e = estart + threadIdx.x; e < eend; e += 256) {
        unsigned p = staged[e];
        atomicAdd(&lrel[(p >> 19) * 3 + ((p >> 17) & 3)], 1);
    }
    __syncthreads();
    for (int j = threadIdx.x; j < BNODES * 3; j += 256) {
        int c = lrel[j];
        lwf[j] = c ? 1.f / (float)c : 0.f;
    }
    // padded exclusive scan over whole-node lengths (2 nodes/thread)
    int t = threadIdx.x;
    int n0 = 2 * t, n1 = 2 * t + 1;
    int ct0 = lrel[n0 * 3] + lrel[n0 * 3 + 1] + lrel[n0 * 3 + 2];
    int ct1 = lrel[n1 * 3] + lrel[n1 * 3 + 1] + lrel[n1 * 3 + 2];
    int pl0 = (ct0 + 3) & ~3, pl1 = (ct1 + 3) & ~3;
    int sum = pl0 + pl1;
    part[t] = sum;
    __syncthreads();
    for (int o = 1; o < 256; o <<= 1) {
        int u = (t >= o) ? part[t - o] : 0;
        __syncthreads();
        part[t] += u;
        __syncthreads();
    }
    int run = ebase + part[t] - sum;
    lbase[n0] = run;       lcnt[n0] = run;
    lbase[n1] = run + pl0; lcnt[n1] = run + pl0;
    if (n0 < nn) { base1[d0 + n0] = run;       plen[d0 + n0] = (unsigned short)pl0; }
    if (n1 < nn) { base1[d0 + n1] = run + pl0; plen[d0 + n1] = (unsigned short)pl1; }
    __syncthreads();
    for (int e = estart + threadIdx.x; e < eend; e += 256) {
        unsigned p = staged[e];
        int dloc = p >> 19;
        unsigned rel = (p >> 17) & 3;
        unsigned src = p & 0x1FFFF;
        float w = lwf[dloc * 3 + rel];
        int slot = atomicAdd(&lcnt[dloc], 1);
        uint2 e2;
        e2.x = (rel * (unsigned)N + src) * 16u;
        e2.y = asu(w);
        edges2[slot] = e2;
        edges1[slot] = (f2bf(w) << 16) | (rel << 6) | (unsigned)combo[src];
    }
    __syncthreads();
    for (int n = threadIdx.x; n < nn; n += 256) {
        int ct = lrel[n * 3] + lrel[n * 3 + 1] + lrel[n * 3 + 2];
        int need = ((ct + 3) & ~3) - ct;          // 0..3 pads, w = 0
        int cur = lcnt[n];
        for (int k = 0; k < need; ++k) {
            uint2 z; z.x = 0u; z.y = 0u;
            edges2[cur + k] = z;
            edges1[cur + k] = 0u;
        }
    }
}

// ---------------------------------------------------------------------------
// K7: fused conv1 = root-table + weighted table-gather, relu -> h1 bf16.
// Wave per node; quarter-wave (16 lanes) per edge, 4 edges/iter; msg table
// (24 KB bf16) in LDS; lane covers 4 dims via uint2.
// ---------------------------------------------------------------------------
__global__ void __launch_bounds__(256) conv1_gather(
        const unsigned* __restrict__ edges1, const int* __restrict__ base1,
        const unsigned short* __restrict__ plen, const unsigned short* __restrict__ msg1t,
        const float* __restrict__ root1t, const unsigned char* __restrict__ combo,
        uint2* __restrict__ h1u2, int N) {
    __shared__ uint2 tab[192 * 16];
    const uint2* m2 = (const uint2*)msg1t;
    for (int t = threadIdx.x; t < 192 * 16; t += 256) tab[t] = m2[t];
    __syncthreads();
    int i = blockIdx.x * 4 + (threadIdx.x >> 6);
    if (i >= N) return;
    int lane = threadIdx.x & 63;
    int l16 = lane & 15, q = lane >> 4;
    int s = base1[i];
    int L = plen[i];
    float f0 = 0.f, f1 = 0.f, f2 = 0.f, f3 = 0.f;
    for (int t2 = 0; t2 < L; t2 += 4) {
        unsigned w = edges1[s + t2 + q];
        float wt = bf2f((unsigned short)(w >> 16));
        uint2 m = tab[(w & 255u) * 16 + l16];
        f0 = fmaf(wt, asf(m.x << 16), f0);
        f1 = fmaf(wt, asf(m.x & 0xFFFF0000u), f1);
        f2 = fmaf(wt, asf(m.y << 16), f2);
        f3 = fmaf(wt, asf(m.y & 0xFFFF0000u), f3);
    }
    f0 += __shfl_xor(f0, 16); f0 += __shfl_xor(f0, 32);
    f1 += __shfl_xor(f1, 16); f1 += __shfl_xor(f1, 32);
    f2 += __shfl_xor(f2, 16); f2 += __shfl_xor(f2, 32);
    f3 += __shfl_xor(f3, 16); f3 += __shfl_xor(f3, 32);
    if (q == 0) {
        const float4 rt = *(const float4*)&root1t[(int)combo[i] * 64 + 4 * l16];
        float v0 = f0 + rt.x; v0 = v0 > 0.f ? v0 : 0.f;
        float v1 = f1 + rt.y; v1 = v1 > 0.f ? v1 : 0.f;
        float v2 = f2 + rt.z; v2 = v2 > 0.f ? v2 : 0.f;
        float v3 = f3 + rt.w; v3 = v3 > 0.f ? v3 : 0.f;
        uint2 o;
        o.x = f2bf(v0) | (f2bf(v1) << 16);
        o.y = f2bf(v2) | (f2bf(v3) << 16);
        h1u2[(size_t)i * 16 + l16] = o;
    }
}

// ---------------------------------------------------------------------------
// K8: gemm_Y. [16,64]@[64,256] MFMA per wave: cols 0..63 -> R = h1@root2+b2,
// cols 64..255 -> Y_r = h1@W2_r. All bf16 out.
// ---------------------------------------------------------------------------
__global__ void __launch_bounds__(256) gemm_Y(
        const unsigned short* __restrict__ h1, const unsigned short* __restrict__ B2f,
        const float* __restrict__ b2, unsigned short* __restrict__ Rb,
        unsigned short* __restrict__ Y, int N) {
    int g = blockIdx.x * 4 + (threadIdx.x >> 6);
    int node0 = g * 16;
    if (node0 >= N) return;
    int lane = threadIdx.x & 63;
    int m = lane & 15, kg = lane >> 4;
    short8 a[2];
#pragma unroll
    for (int kt = 0; kt < 2; ++kt)
        a[kt] = *(const short8*)(h1 + (size_t)(node0 + m) * 64 + kt * 32 + kg * 8);
#pragma unroll
    for (int nt = 0; nt < 16; ++nt) {
        floatx4 c = {0.f, 0.f, 0.f, 0.f};
#pragma unroll
        for (int kt = 0; kt < 2; ++kt) {
            short8 b = *(const short8*)(B2f + ((nt * 2 + kt) * 64 + lane) * 8);
            c = __builtin_amdgcn_mfma_f32_16x16x32_bf16(a[kt], b, c, 0, 0, 0);
        }
        if (nt < 4) {
            int col = nt * 16 + m;
            float bias = b2[col];
#pragma unroll
            for (int q = 0; q < 4; ++q) {
                int node = node0 + kg * 4 + q;
                if (node < N) Rb[(size_t)node * 64 + col] = (unsigned short)f2bf(c[q] + bias);
            }
        } else {
            int r = (nt - 4) >> 2;
            int ycol = ((nt - 4) & 3) * 16 + m;
#pragma unroll
            for (int q = 0; q < 4; ++q) {
                int node = node0 + kg * 4 + q;
                if (node < N)
                    Y[((size_t)r * N + node) * 64 + ycol] = (unsigned short)f2bf(c[q]);
            }
        }
    }
}

// ---------------------------------------------------------------------------
// K9: conv2 gather. Wave per node; quarter-wave per edge, single weighted
// accumulator (rel folded into the Y offset + weight). h2 = R + sum (pre-relu).
// ---------------------------------------------------------------------------
__global__ void __launch_bounds__(256) conv2_gather(
        const uint2* __restrict__ edges2, const int* __restrict__ base1,
        const unsigned short* __restrict__ plen, const uint2* __restrict__ Yu2,
        const uint2* __restrict__ Ru2, uint2* __restrict__ h2u2, int N) {
    int i = blockIdx.x * 4 + (threadIdx.x >> 6);
    if (i >= N) return;
    int lane = threadIdx.x & 63;
    int l16 = lane & 15, q = lane >> 4;
    int s = base1[i];
    int L = plen[i];
    float f0 = 0.f, f1 = 0.f, f2 = 0.f, f3 = 0.f;
    for (int t2 = 0; t2 < L; t2 += 4) {
        uint2 e = edges2[s + t2 + q];
        float wt = asf(e.y);
        uint2 v = Yu2[(size_t)e.x + l16];
        f0 = fmaf(wt, asf(v.x << 16), f0);
        f1 = fmaf(wt, asf(v.x & 0xFFFF0000u), f1);
        f2 = fmaf(wt, asf(v.y << 16), f2);
        f3 = fmaf(wt, asf(v.y & 0xFFFF0000u), f3);
    }
    f0 += __shfl_xor(f0, 16); f0 += __shfl_xor(f0, 32);
    f1 += __shfl_xor(f1, 16); f1 += __shfl_xor(f1, 32);
    f2 += __shfl_xor(f2, 16); f2 += __shfl_xor(f2, 32);
    f3 += __shfl_xor(f3, 16); f3 += __shfl_xor(f3, 32);
    if (q == 0) {
        uint2 rb = Ru2[(size_t)i * 16 + l16];
        f0 += asf(rb.x << 16);
        f1 += asf(rb.x & 0xFFFF0000u);
        f2 += asf(rb.y << 16);
        f3 += asf(rb.y & 0xFFFF0000u);
        uint2 o;
        o.x = f2bf(f0) | (f2bf(f1) << 16);
        o.y = f2bf(f2) | (f2bf(f3) << 16);
        h2u2[(size_t)i * 16 + l16] = o;
    }
}

// ---------------------------------------------------------------------------
// K10: mean-pool (sorted batch -> binary search) + classifier; relu folded.
// ---------------------------------------------------------------------------
__global__ void __launch_bounds__(64) pool_cls(
        const unsigned short* __restrict__ h2, const int* __restrict__ batch,
        const float* __restrict__ cls_w, const float* __restrict__ cls_b,
        float* __restrict__ out, int N, int G) {
    int g = blockIdx.x, lane = threadIdx.x;
    auto lb = [&](int key) {
        int lo = 0, hi = N;
        while (lo < hi) { int mid = (lo + hi) >> 1; if (batch[mid] < key) lo = mid + 1; else hi = mid; }
        return lo;
    };
    int start = lb(g), end = lb(g + 1);
    float sum = 0.f;
    for (int i = start; i < end; ++i) {
        float v = bf2f(h2[(size_t)i * 64 + lane]);
        sum += v > 0.f ? v : 0.f;
    }
    int cntn = end - start;
    float pooled = sum / (float)(cntn > 0 ? cntn : 1);
    __shared__ float ps[64];
    ps[lane] = pooled;
    __syncthreads();
    if (lane < 10) {
        float o = cls_b[lane];
#pragma unroll
        for (int j = 0; j < 64; ++j) o = fmaf(ps[j], cls_w[j * 10 + lane], o);
        out[g * 10 + lane] = o;
    }
}

// ---------------------------------------------------------------------------
extern "C" void kernel_launch(void* const* d_in, const int* in_sizes, int n_in,
                              void* d_out, int out_size, void* d_ws, size_t ws_size,
                              hipStream_t stream) {
    const int*   node_x = (const int*)d_in[0];
    const int*   ei     = (const int*)d_in[1];
    const int*   et     = (const int*)d_in[2];
    const int*   batch  = (const int*)d_in[3];
    const float* pre_w  = (const float*)d_in[4];
    const float* pre_b  = (const float*)d_in[5];
    const float* w1     = (const float*)d_in[6];
    const float* root1  = (const float*)d_in[7];
    const float* b1     = (const float*)d_in[8];
    const float* w2     = (const float*)d_in[9];
    const float* root2  = (const float*)d_in[10];
    const float* b2     = (const float*)d_in[11];
    const float* cls_w  = (const float*)d_in[12];
    const float* cls_b  = (const float*)d_in[13];
    float* out = (float*)d_out;

    int N = in_sizes[0] / 2;
    int E = in_sizes[1] / 2;
    int G = out_size / 10;

    int NB = (N + BNODES - 1) >> BSH;
    int chunk = (E + NBLK_A - 1) / NBLK_A;
    int nh = NB * NBLK_A;
    int nscan = (nh + 1023) / 1024;
    int EP = E + NB * BNODES * 3;      // whole-node pads (<=3/node)

    char* ws = (char*)d_ws;
    size_t off_b = 0;
    auto alloc = [&](size_t bytes) {
        void* p = ws + off_b;
        off_b = (off_b + bytes + 255) & ~(size_t)255;
        return p;
    };
    unsigned short* msg1t  = (unsigned short*)alloc(192 * 64 * sizeof(short));
    float*          root1t = (float*)alloc(64 * 64 * sizeof(float));
    unsigned short* B2f    = (unsigned short*)alloc(16 * 2 * 64 * 8 * sizeof(short));
    unsigned char*  combo  = (unsigned char*)alloc((size_t)N + 64);
    int*            hist   = (int*)alloc((size_t)nh * sizeof(int));
    int*            hoff   = (int*)alloc((size_t)nh * sizeof(int));
    int*            bsums  = (int*)alloc(128 * sizeof(int));
    unsigned*       staged = (unsigned*)alloc((size_t)E * sizeof(unsigned));
    unsigned*       edges1 = (unsigned*)alloc((size_t)EP * sizeof(unsigned));
    uint2*          edges2 = (uint2*)alloc((size_t)EP * sizeof(uint2));
    int*            base1  = (int*)alloc(((size_t)N + 8) * sizeof(int));
    unsigned short* plen   = (unsigned short*)alloc(((size_t)N + 8) * sizeof(short));
    unsigned short* h1     = (unsigned short*)alloc((size_t)(N + 16) * 64 * sizeof(short));
    unsigned short* Rb     = (unsigned short*)alloc((size_t)N * 64 * sizeof(short));
    unsigned short* Y      = (unsigned short*)alloc((size_t)3 * N * 64 * sizeof(short));
    unsigned short* h2     = (unsigned short*)alloc((size_t)N * 64 * sizeof(short));

    build_tables<<<64, 64, 0, stream>>>(pre_w, pre_b, w1, root1, b1, msg1t, root1t);
    prep_B2<<<64, 256, 0, stream>>>(root2, w2, B2f);
    combo_kernel<<<(N + 255) / 256, 256, 0, stream>>>(node_x, combo, N);

    hist_kernel<<<NBLK_A, 256, 0, stream>>>(ei, hist, E, NB, chunk);
    scan1<<<nscan, 1024, 0, stream>>>(hist, hoff, bsums, nh);
    scan2<<<1, 128, 0, stream>>>(bsums, nscan);
    scan3<<<nscan, 1024, 0, stream>>>(hoff, bsums, nh);
    place_kernel<<<NBLK_A, 256, 0, stream>>>(ei, et, hoff, staged, E, NB, chunk);
    finalize_kernel<<<NB, 256, 0, stream>>>(staged, hoff, combo, edges1, edges2,
                                            base1, plen, E, N, NB);

    conv1_gather<<<(N + 3) / 4, 256, 0, stream>>>(edges1, base1, plen, msg1t, root1t,
                                                  combo, (uint2*)h1, N);
    gemm_Y<<<((N + 15) / 16 + 3) / 4, 256, 0, stream>>>(h1, B2f, b2, Rb, Y, N);
    conv2_gather<<<(N + 3) / 4, 256, 0, stream>>>(edges2, base1, plen, (const uint2*)Y,
                                                  (const uint2*)Rb, (uint2*)h2, N);
    pool_cls<<<G, 64, 0, stream>>>(h2, batch, cls_w, cls_b, out, N, G);
}

// Round 10
// 263.417 us; speedup vs baseline: 1.0722x; 1.0722x over previous
//
#include <hip/hip_runtime.h>

#define BSH 9              // 512 nodes per dst bucket
#define BNODES 512
#define NBLK_A 256         // blocks in hist/place passes

typedef __attribute__((ext_vector_type(8))) short short8;
typedef __attribute__((ext_vector_type(4))) float floatx4;

static __device__ inline float bf2f(unsigned short u) {
    union { unsigned int i; float f; } v; v.i = ((unsigned int)u) << 16; return v.f;
}
static __device__ inline unsigned f2bf(float f) {
    union { float f; unsigned int i; } v; v.f = f;
    unsigned int x = v.i;
    return (x + 0x7FFF + ((x >> 16) & 1)) >> 16;  // RNE
}
static __device__ inline float asf(unsigned int u) {
    union { unsigned int i; float f; } v; v.i = u; return v.f;
}
static __device__ inline unsigned asu(float f) {
    union { float f; unsigned int i; } v; v.f = f; return v.i;
}

// ---------------------------------------------------------------------------
// K1: tables. msg1t[(r*64+combo)][64] bf16 (= x1 @ W1_r), root1t[64][64] f32
// ---------------------------------------------------------------------------
__global__ void build_tables(const float* __restrict__ pre_w, const float* __restrict__ pre_b,
                             const float* __restrict__ w1, const float* __restrict__ root1,
                             const float* __restrict__ b1,
                             unsigned short* __restrict__ msg1t, float* __restrict__ root1t) {
    int combo = blockIdx.x, j = threadIdx.x;
    __shared__ float x1s[32];
    int s = combo >> 3, c = combo & 7;
    if (j < 32) {
        float v = pre_w[s * 32 + j] + pre_w[(8 + c) * 32 + j] + pre_b[j];
        x1s[j] = v > 0.f ? v : 0.f;
    }
    __syncthreads();
    float acc = b1[j];
#pragma unroll
    for (int k = 0; k < 32; ++k) acc = fmaf(x1s[k], root1[k * 64 + j], acc);
    root1t[combo * 64 + j] = acc;
    for (int r = 0; r < 3; ++r) {
        float a = 0.f;
#pragma unroll
        for (int k = 0; k < 32; ++k) a = fmaf(x1s[k], w1[(r * 32 + k) * 64 + j], a);
        msg1t[((r << 6) | combo) * 64 + j] = (unsigned short)f2bf(a);
    }
}

// ---------------------------------------------------------------------------
// K2: B-fragments for the [64,256] matrix [root2 | W2_0 | W2_1 | W2_2].
// ---------------------------------------------------------------------------
__global__ void prep_B2(const float* __restrict__ root2, const float* __restrict__ w2,
                        unsigned short* __restrict__ B2f) {
    int t = blockIdx.x * blockDim.x + threadIdx.x;
    if (t >= 16 * 2 * 64 * 8) return;
    int i = t & 7, l = (t >> 3) & 63, kt = (t >> 9) & 1, nt = t >> 10;
    int k = kt * 32 + ((l >> 4) * 8) + i;
    int col = nt * 16 + (l & 15);
    float v;
    if (col < 64) v = root2[k * 64 + col];
    else {
        int r = (col - 64) >> 6, wcol = (col - 64) & 63;
        v = w2[(r * 64 + k) * 64 + wcol];
    }
    B2f[t] = (unsigned short)f2bf(v);
}

// K3: combo[i] as u8
__global__ void combo_kernel(const int* __restrict__ node_x, unsigned char* __restrict__ combo, int N) {
    int i = blockIdx.x * blockDim.x + threadIdx.x;
    if (i < N) combo[i] = (unsigned char)(node_x[2 * i] * 8 + node_x[2 * i + 1]);
}

// ---------------------------------------------------------------------------
// K4 (pass A0): per-block dst-bucket histogram. hist[b*NBLK_A + blk]
// ---------------------------------------------------------------------------
__global__ void __launch_bounds__(256) hist_kernel(const int* __restrict__ ei,
                                                   int* __restrict__ hist, int E, int NB, int chunk) {
    __shared__ int lh[256];
    for (int t = threadIdx.x; t < NB; t += 256) lh[t] = 0;
    __syncthreads();
    int s = blockIdx.x * chunk, e1 = min(E, s + chunk);
    for (int e = s + threadIdx.x; e < e1; e += 256)
        atomicAdd(&lh[ei[E + e] >> BSH], 1);
    __syncthreads();
    for (int b = threadIdx.x; b < NB; b += 256) hist[b * NBLK_A + blockIdx.x] = lh[b];
}

// generic exclusive scan (3 kernels)
__global__ void scan1(const int* __restrict__ in, int* __restrict__ out,
                      int* __restrict__ bsums, int n) {
    __shared__ int s[1024];
    int i = blockIdx.x * 1024 + threadIdx.x;
    int d = (i < n) ? in[i] : 0;
    s[threadIdx.x] = d;
    __syncthreads();
    for (int off = 1; off < 1024; off <<= 1) {
        int v = (threadIdx.x >= off) ? s[threadIdx.x - off] : 0;
        __syncthreads();
        s[threadIdx.x] += v;
        __syncthreads();
    }
    if (i < n) out[i] = s[threadIdx.x] - d;
    if (threadIdx.x == 1023) bsums[blockIdx.x] = s[1023];
}
__global__ void scan2(int* __restrict__ bsums, int nb) {
    __shared__ int s[128];
    int v = (threadIdx.x < nb) ? bsums[threadIdx.x] : 0;
    s[threadIdx.x] = v;
    __syncthreads();
    for (int off = 1; off < 128; off <<= 1) {
        int u = (threadIdx.x >= off) ? s[threadIdx.x - off] : 0;
        __syncthreads();
        s[threadIdx.x] += u;
        __syncthreads();
    }
    if (threadIdx.x < nb) bsums[threadIdx.x] = s[threadIdx.x] - v;
}
__global__ void scan3(int* __restrict__ out, const int* __restrict__ bsums, int n) {
    int i = blockIdx.x * 1024 + threadIdx.x;
    if (i < n) out[i] += bsums[blockIdx.x];
}

// ---------------------------------------------------------------------------
// K5 (pass A1): place edges into dst-buckets. staged = dloc<<19 | rel<<17 | src
// ---------------------------------------------------------------------------
__global__ void __launch_bounds__(256) place_kernel(const int* __restrict__ ei, const int* __restrict__ et,
                                                    const int* __restrict__ off, unsigned* __restrict__ staged,
                                                    int E, int NB, int chunk) {
    __shared__ int lh[256];
    for (int t = threadIdx.x; t < NB; t += 256) lh[t] = 0;
    __syncthreads();
    int s = blockIdx.x * chunk, e1 = min(E, s + chunk);
    for (int e = s + threadIdx.x; e < e1; e += 256) {
        int d = ei[E + e];
        int b = d >> BSH;
        int lr = atomicAdd(&lh[b], 1);
        int pos = off[b * NBLK_A + blockIdx.x] + lr;
        staged[pos] = ((unsigned)(d & (BNODES - 1)) << 19) | ((unsigned)et[e] << 17) | (unsigned)ei[e];
    }
}

// ---------------------------------------------------------------------------
// K6 (pass B): finalize into whole-node x4-padded CSR with per-edge
// precomputed weight w = 1/cnt(dst,rel).
//   edges2[e] = { (rel*N+src)*16 (uint2 row offset into Y), asu(w) }
//   edges1[e] = f2bf(w)<<16 | rel<<6 | combo(src)      (pads: all zero)
//   base1[i], plen[i] (padded length, multiple of 4)
// Bucket capacity = raw + 3*BNODES.
// ---------------------------------------------------------------------------
__global__ void __launch_bounds__(256) finalize_kernel(
        const unsigned* __restrict__ staged, const int* __restrict__ off,
        const unsigned char* __restrict__ combo,
        unsigned* __restrict__ edges1, uint2* __restrict__ edges2,
        int* __restrict__ base1, unsigned short* __restrict__ plen,
        int E, int N, int NB) {
    __shared__ int lrel[BNODES * 3];   // per-(node,rel) counts (stay counts)
    __shared__ float lwf[BNODES * 3];  // 1/count
    __shared__ int lcnt[BNODES];       // placement cursors
    __shared__ int part[256];
    int blk = blockIdx.x;
    int d0 = blk * BNODES;
    int nn = min(BNODES, N - d0);
    int estart = off[blk * NBLK_A];
    int eend = (blk == NB - 1) ? E : off[(blk + 1) * NBLK_A];
    int ebase = estart + blk * (BNODES * 3);   // padded-capacity base
    for (int t = threadIdx.x; t < BNODES * 3; t += 256) lrel[t] = 0;
    __syncthreads();
    for (int e = estart + threadIdx.x; e < eend; e += 256) {
        unsigned p = staged[e];
        atomicAdd(&lrel[(p >> 19) * 3 + ((p >> 17) & 3)], 1);
    }
    __syncthreads();
    for (int j = threadIdx.x; j < BNODES * 3; j += 256) {
        int c = lrel[j];
        lwf[j] = c ? 1.f / (float)c : 0.f;
    }
    // padded exclusive scan over whole-node lengths (2 nodes/thread)
    int t = threadIdx.x;
    int n0 = 2 * t, n1 = 2 * t + 1;
    int ct0 = lrel[n0 * 3] + lrel[n0 * 3 + 1] + lrel[n0 * 3 + 2];
    int ct1 = lrel[n1 * 3] + lrel[n1 * 3 + 1] + lrel[n1 * 3 + 2];
    int pl0 = (ct0 + 3) & ~3, pl1 = (ct1 + 3) & ~3;
    int sum = pl0 + pl1;
    part[t] = sum;
    __syncthreads();
    for (int o = 1; o < 256; o <<= 1) {
        int u = (t >= o) ? part[t - o] : 0;
        __syncthreads();
        part[t] += u;
        __syncthreads();
    }
    int run = ebase + part[t] - sum;
    lcnt[n0] = run;
    lcnt[n1] = run + pl0;
    if (n0 < nn) { base1[d0 + n0] = run;       plen[d0 + n0] = (unsigned short)pl0; }
    if (n1 < nn) { base1[d0 + n1] = run + pl0; plen[d0 + n1] = (unsigned short)pl1; }
    __syncthreads();
    for (int e = estart + threadIdx.x; e < eend; e += 256) {
        unsigned p = staged[e];
        int dloc = p >> 19;
        unsigned rel = (p >> 17) & 3;
        unsigned src = p & 0x1FFFF;
        float w = lwf[dloc * 3 + rel];
        int slot = atomicAdd(&lcnt[dloc], 1);
        uint2 e2;
        e2.x = (rel * (unsigned)N + src) * 16u;
        e2.y = asu(w);
        edges2[slot] = e2;
        edges1[slot] = (f2bf(w) << 16) | (rel << 6) | (unsigned)combo[src];
    }
    __syncthreads();
    for (int n = threadIdx.x; n < nn; n += 256) {
        int ct = lrel[n * 3] + lrel[n * 3 + 1] + lrel[n * 3 + 2];
        int need = ((ct + 3) & ~3) - ct;          // 0..3 pads, w = 0
        int cur = lcnt[n];
        for (int k = 0; k < need; ++k) {
            uint2 z; z.x = 0u; z.y = 0u;
            edges2[cur + k] = z;
            edges1[cur + k] = 0u;
        }
    }
}

// ---------------------------------------------------------------------------
// K7: fused conv1 = root-table + weighted table-gather, relu -> h1 bf16.
// GRID-STRIDE persistent blocks (fill 24KB LDS table once per block, then
// ~48 nodes each). LDS rows padded to 17 uint2 to break the 4-way bank
// conflict between the 4 quarter-waves.
// ---------------------------------------------------------------------------
__global__ void __launch_bounds__(256) conv1_gather(
        const unsigned* __restrict__ edges1, const int* __restrict__ base1,
        const unsigned short* __restrict__ plen, const unsigned short* __restrict__ msg1t,
        const float* __restrict__ root1t, const unsigned char* __restrict__ combo,
        uint2* __restrict__ h1u2, int N, int nGrp) {
    __shared__ uint2 tab[192 * 17];
    const uint2* m2 = (const uint2*)msg1t;
    for (int t = threadIdx.x; t < 192 * 16; t += 256)
        tab[(t >> 4) * 17 + (t & 15)] = m2[t];
    __syncthreads();
    int lane = threadIdx.x & 63;
    int w = threadIdx.x >> 6;
    int l16 = lane & 15, q = lane >> 4;
    for (int g = blockIdx.x; g < nGrp; g += gridDim.x) {
        int i = g * 4 + w;
        if (i >= N) continue;
        int s = base1[i];
        int L = plen[i];
        float f0 = 0.f, f1 = 0.f, f2 = 0.f, f3 = 0.f;
        for (int t2 = 0; t2 < L; t2 += 4) {
            unsigned ew = edges1[s + t2 + q];
            float wt = bf2f((unsigned short)(ew >> 16));
            uint2 m = tab[(ew & 255u) * 17 + l16];
            f0 = fmaf(wt, asf(m.x << 16), f0);
            f1 = fmaf(wt, asf(m.x & 0xFFFF0000u), f1);
            f2 = fmaf(wt, asf(m.y << 16), f2);
            f3 = fmaf(wt, asf(m.y & 0xFFFF0000u), f3);
        }
        f0 += __shfl_xor(f0, 16); f0 += __shfl_xor(f0, 32);
        f1 += __shfl_xor(f1, 16); f1 += __shfl_xor(f1, 32);
        f2 += __shfl_xor(f2, 16); f2 += __shfl_xor(f2, 32);
        f3 += __shfl_xor(f3, 16); f3 += __shfl_xor(f3, 32);
        if (q == 0) {
            const float4 rt = *(const float4*)&root1t[(int)combo[i] * 64 + 4 * l16];
            float v0 = f0 + rt.x; v0 = v0 > 0.f ? v0 : 0.f;
            float v1 = f1 + rt.y; v1 = v1 > 0.f ? v1 : 0.f;
            float v2 = f2 + rt.z; v2 = v2 > 0.f ? v2 : 0.f;
            float v3 = f3 + rt.w; v3 = v3 > 0.f ? v3 : 0.f;
            uint2 o;
            o.x = f2bf(v0) | (f2bf(v1) << 16);
            o.y = f2bf(v2) | (f2bf(v3) << 16);
            h1u2[(size_t)i * 16 + l16] = o;
        }
    }
}

// ---------------------------------------------------------------------------
// K8: gemm_Y. [16,64]@[64,256] MFMA per wave: cols 0..63 -> R = h1@root2+b2,
// cols 64..255 -> Y_r = h1@W2_r. All bf16 out.
// ---------------------------------------------------------------------------
__global__ void __launch_bounds__(256) gemm_Y(
        const unsigned short* __restrict__ h1, const unsigned short* __restrict__ B2f,
        const float* __restrict__ b2, unsigned short* __restrict__ Rb,
        unsigned short* __restrict__ Y, int N) {
    int g = blockIdx.x * 4 + (threadIdx.x >> 6);
    int node0 = g * 16;
    if (node0 >= N) return;
    int lane = threadIdx.x & 63;
    int m = lane & 15, kg = lane >> 4;
    short8 a[2];
#pragma unroll
    for (int kt = 0; kt < 2; ++kt)
        a[kt] = *(const short8*)(h1 + (size_t)(node0 + m) * 64 + kt * 32 + kg * 8);
#pragma unroll
    for (int nt = 0; nt < 16; ++nt) {
        floatx4 c = {0.f, 0.f, 0.f, 0.f};
#pragma unroll
        for (int kt = 0; kt < 2; ++kt) {
            short8 b = *(const short8*)(B2f + ((nt * 2 + kt) * 64 + lane) * 8);
            c = __builtin_amdgcn_mfma_f32_16x16x32_bf16(a[kt], b, c, 0, 0, 0);
        }
        if (nt < 4) {
            int col = nt * 16 + m;
            float bias = b2[col];
#pragma unroll
            for (int q = 0; q < 4; ++q) {
                int node = node0 + kg * 4 + q;
                if (node < N) Rb[(size_t)node * 64 + col] = (unsigned short)f2bf(c[q] + bias);
            }
        } else {
            int r = (nt - 4) >> 2;
            int ycol = ((nt - 4) & 3) * 16 + m;
#pragma unroll
            for (int q = 0; q < 4; ++q) {
                int node = node0 + kg * 4 + q;
                if (node < N)
                    Y[((size_t)r * N + node) * 64 + ycol] = (unsigned short)f2bf(c[q]);
            }
        }
    }
}

// ---------------------------------------------------------------------------
// K9: conv2 gather. Wave per node; quarter-wave per edge, single weighted
// accumulator (rel folded into the Y offset + weight). h2 = R + sum (pre-relu).
// ---------------------------------------------------------------------------
__global__ void __launch_bounds__(256) conv2_gather(
        const uint2* __restrict__ edges2, const int* __restrict__ base1,
        const unsigned short* __restrict__ plen, const uint2* __restrict__ Yu2,
        const uint2* __restrict__ Ru2, uint2* __restrict__ h2u2, int N) {
    int i = blockIdx.x * 4 + (threadIdx.x >> 6);
    if (i >= N) return;
    int lane = threadIdx.x & 63;
    int l16 = lane & 15, q = lane >> 4;
    int s = base1[i];
    int L = plen[i];
    float f0 = 0.f, f1 = 0.f, f2 = 0.f, f3 = 0.f;
    for (int t2 = 0; t2 < L; t2 += 4) {
        uint2 e = edges2[s + t2 + q];
        float wt = asf(e.y);
        uint2 v = Yu2[(size_t)e.x + l16];
        f0 = fmaf(wt, asf(v.x << 16), f0);
        f1 = fmaf(wt, asf(v.x & 0xFFFF0000u), f1);
        f2 = fmaf(wt, asf(v.y << 16), f2);
        f3 = fmaf(wt, asf(v.y & 0xFFFF0000u), f3);
    }
    f0 += __shfl_xor(f0, 16); f0 += __shfl_xor(f0, 32);
    f1 += __shfl_xor(f1, 16); f1 += __shfl_xor(f1, 32);
    f2 += __shfl_xor(f2, 16); f2 += __shfl_xor(f2, 32);
    f3 += __shfl_xor(f3, 16); f3 += __shfl_xor(f3, 32);
    if (q == 0) {
        uint2 rb = Ru2[(size_t)i * 16 + l16];
        f0 += asf(rb.x << 16);
        f1 += asf(rb.x & 0xFFFF0000u);
        f2 += asf(rb.y << 16);
        f3 += asf(rb.y & 0xFFFF0000u);
        uint2 o;
        o.x = f2bf(f0) | (f2bf(f1) << 16);
        o.y = f2bf(f2) | (f2bf(f3) << 16);
        h2u2[(size_t)i * 16 + l16] = o;
    }
}

// ---------------------------------------------------------------------------
// K10: mean-pool (sorted batch -> binary search) + classifier; relu folded.
// ---------------------------------------------------------------------------
__global__ void __launch_bounds__(64) pool_cls(
        const unsigned short* __restrict__ h2, const int* __restrict__ batch,
        const float* __restrict__ cls_w, const float* __restrict__ cls_b,
        float* __restrict__ out, int N, int G) {
    int g = blockIdx.x, lane = threadIdx.x;
    auto lb = [&](int key) {
        int lo = 0, hi = N;
        while (lo < hi) { int mid = (lo + hi) >> 1; if (batch[mid] < key) lo = mid + 1; else hi = mid; }
        return lo;
    };
    int start = lb(g), end = lb(g + 1);
    float sum = 0.f;
    for (int i = start; i < end; ++i) {
        float v = bf2f(h2[(size_t)i * 64 + lane]);
        sum += v > 0.f ? v : 0.f;
    }
    int cntn = end - start;
    float pooled = sum / (float)(cntn > 0 ? cntn : 1);
    __shared__ float ps[64];
    ps[lane] = pooled;
    __syncthreads();
    if (lane < 10) {
        float o = cls_b[lane];
#pragma unroll
        for (int j = 0; j < 64; ++j) o = fmaf(ps[j], cls_w[j * 10 + lane], o);
        out[g * 10 + lane] = o;
    }
}

// ---------------------------------------------------------------------------
extern "C" void kernel_launch(void* const* d_in, const int* in_sizes, int n_in,
                              void* d_out, int out_size, void* d_ws, size_t ws_size,
                              hipStream_t stream) {
    const int*   node_x = (const int*)d_in[0];
    const int*   ei     = (const int*)d_in[1];
    const int*   et     = (const int*)d_in[2];
    const int*   batch  = (const int*)d_in[3];
    const float* pre_w  = (const float*)d_in[4];
    const float* pre_b  = (const float*)d_in[5];
    const float* w1     = (const float*)d_in[6];
    const float* root1  = (const float*)d_in[7];
    const float* b1     = (const float*)d_in[8];
    const float* w2     = (const float*)d_in[9];
    const float* root2  = (const float*)d_in[10];
    const float* b2     = (const float*)d_in[11];
    const float* cls_w  = (const float*)d_in[12];
    const float* cls_b  = (const float*)d_in[13];
    float* out = (float*)d_out;

    int N = in_sizes[0] / 2;
    int E = in_sizes[1] / 2;
    int G = out_size / 10;

    int NB = (N + BNODES - 1) >> BSH;
    int chunk = (E + NBLK_A - 1) / NBLK_A;
    int nh = NB * NBLK_A;
    int nscan = (nh + 1023) / 1024;
    int EP = E + NB * BNODES * 3;      // whole-node pads (<=3/node)

    char* ws = (char*)d_ws;
    size_t off_b = 0;
    auto alloc = [&](size_t bytes) {
        void* p = ws + off_b;
        off_b = (off_b + bytes + 255) & ~(size_t)255;
        return p;
    };
    unsigned short* msg1t  = (unsigned short*)alloc(192 * 64 * sizeof(short));
    float*          root1t = (float*)alloc(64 * 64 * sizeof(float));
    unsigned short* B2f    = (unsigned short*)alloc(16 * 2 * 64 * 8 * sizeof(short));
    unsigned char*  combo  = (unsigned char*)alloc((size_t)N + 64);
    int*            hist   = (int*)alloc((size_t)nh * sizeof(int));
    int*            hoff   = (int*)alloc((size_t)nh * sizeof(int));
    int*            bsums  = (int*)alloc(128 * sizeof(int));
    unsigned*       staged = (unsigned*)alloc((size_t)E * sizeof(unsigned));
    unsigned*       edges1 = (unsigned*)alloc((size_t)EP * sizeof(unsigned));
    uint2*          edges2 = (uint2*)alloc((size_t)EP * sizeof(uint2));
    int*            base1  = (int*)alloc(((size_t)N + 8) * sizeof(int));
    unsigned short* plen   = (unsigned short*)alloc(((size_t)N + 8) * sizeof(short));
    unsigned short* h1     = (unsigned short*)alloc((size_t)(N + 16) * 64 * sizeof(short));
    unsigned short* Rb     = (unsigned short*)alloc((size_t)N * 64 * sizeof(short));
    unsigned short* Y      = (unsigned short*)alloc((size_t)3 * N * 64 * sizeof(short));
    unsigned short* h2     = (unsigned short*)alloc((size_t)N * 64 * sizeof(short));

    build_tables<<<64, 64, 0, stream>>>(pre_w, pre_b, w1, root1, b1, msg1t, root1t);
    prep_B2<<<64, 256, 0, stream>>>(root2, w2, B2f);
    combo_kernel<<<(N + 255) / 256, 256, 0, stream>>>(node_x, combo, N);

    hist_kernel<<<NBLK_A, 256, 0, stream>>>(ei, hist, E, NB, chunk);
    scan1<<<nscan, 1024, 0, stream>>>(hist, hoff, bsums, nh);
    scan2<<<1, 128, 0, stream>>>(bsums, nscan);
    scan3<<<nscan, 1024, 0, stream>>>(hoff, bsums, nh);
    place_kernel<<<NBLK_A, 256, 0, stream>>>(ei, et, hoff, staged, E, NB, chunk);
    finalize_kernel<<<NB, 256, 0, stream>>>(staged, hoff, combo, edges1, edges2,
                                            base1, plen, E, N, NB);

    int nGrp = (N + 3) / 4;
    conv1_gather<<<2048, 256, 0, stream>>>(edges1, base1, plen, msg1t, root1t,
                                           combo, (uint2*)h1, N, nGrp);
    gemm_Y<<<((N + 15) / 16 + 3) / 4, 256, 0, stream>>>(h1, B2f, b2, Rb, Y, N);
    conv2_gather<<<(N + 3) / 4, 256, 0, stream>>>(edges2, base1, plen, (const uint2*)Y,
                                                  (const uint2*)Rb, (uint2*)h2, N);
    pool_cls<<<G, 64, 0, stream>>>(h2, batch, cls_w, cls_b, out, N, G);
}

// Round 11
// 260.484 us; speedup vs baseline: 1.0842x; 1.0113x over previous
//
#include <hip/hip_runtime.h>

#define BSH 9              // 512 nodes per dst bucket
#define BNODES 512
#define NBLK_A 256         // blocks in hist/place passes

typedef __attribute__((ext_vector_type(8))) short short8;
typedef __attribute__((ext_vector_type(4))) float floatx4;

static __device__ inline float bf2f(unsigned short u) {
    union { unsigned int i; float f; } v; v.i = ((unsigned int)u) << 16; return v.f;
}
static __device__ inline unsigned f2bf(float f) {
    union { float f; unsigned int i; } v; v.f = f;
    unsigned int x = v.i;
    return (x + 0x7FFF + ((x >> 16) & 1)) >> 16;  // RNE
}
static __device__ inline float asf(unsigned int u) {
    union { unsigned int i; float f; } v; v.i = u; return v.f;
}
static __device__ inline unsigned asu(float f) {
    union { float f; unsigned int i; } v; v.f = f; return v.i;
}

// ---------------------------------------------------------------------------
// K1: tables. msg1t[(r*64+combo)][64] bf16 (= x1 @ W1_r), root1t[64][64] f32
// ---------------------------------------------------------------------------
__global__ void build_tables(const float* __restrict__ pre_w, const float* __restrict__ pre_b,
                             const float* __restrict__ w1, const float* __restrict__ root1,
                             const float* __restrict__ b1,
                             unsigned short* __restrict__ msg1t, float* __restrict__ root1t) {
    int combo = blockIdx.x, j = threadIdx.x;
    __shared__ float x1s[32];
    int s = combo >> 3, c = combo & 7;
    if (j < 32) {
        float v = pre_w[s * 32 + j] + pre_w[(8 + c) * 32 + j] + pre_b[j];
        x1s[j] = v > 0.f ? v : 0.f;
    }
    __syncthreads();
    float acc = b1[j];
#pragma unroll
    for (int k = 0; k < 32; ++k) acc = fmaf(x1s[k], root1[k * 64 + j], acc);
    root1t[combo * 64 + j] = acc;
    for (int r = 0; r < 3; ++r) {
        float a = 0.f;
#pragma unroll
        for (int k = 0; k < 32; ++k) a = fmaf(x1s[k], w1[(r * 32 + k) * 64 + j], a);
        msg1t[((r << 6) | combo) * 64 + j] = (unsigned short)f2bf(a);
    }
}

// ---------------------------------------------------------------------------
// K2: B-fragments for the [64,256] matrix [root2 | W2_0 | W2_1 | W2_2].
// ---------------------------------------------------------------------------
__global__ void prep_B2(const float* __restrict__ root2, const float* __restrict__ w2,
                        unsigned short* __restrict__ B2f) {
    int t = blockIdx.x * blockDim.x + threadIdx.x;
    if (t >= 16 * 2 * 64 * 8) return;
    int i = t & 7, l = (t >> 3) & 63, kt = (t >> 9) & 1, nt = t >> 10;
    int k = kt * 32 + ((l >> 4) * 8) + i;
    int col = nt * 16 + (l & 15);
    float v;
    if (col < 64) v = root2[k * 64 + col];
    else {
        int r = (col - 64) >> 6, wcol = (col - 64) & 63;
        v = w2[(r * 64 + k) * 64 + wcol];
    }
    B2f[t] = (unsigned short)f2bf(v);
}

// K3: combo[i] as u8
__global__ void combo_kernel(const int* __restrict__ node_x, unsigned char* __restrict__ combo, int N) {
    int i = blockIdx.x * blockDim.x + threadIdx.x;
    if (i < N) combo[i] = (unsigned char)(node_x[2 * i] * 8 + node_x[2 * i + 1]);
}

// ---------------------------------------------------------------------------
// K4 (pass A0): per-block dst-bucket histogram. hist[b*NBLK_A + blk]
// ---------------------------------------------------------------------------
__global__ void __launch_bounds__(256) hist_kernel(const int* __restrict__ ei,
                                                   int* __restrict__ hist, int E, int NB, int chunk) {
    __shared__ int lh[256];
    for (int t = threadIdx.x; t < NB; t += 256) lh[t] = 0;
    __syncthreads();
    int s = blockIdx.x * chunk, e1 = min(E, s + chunk);
    for (int e = s + threadIdx.x; e < e1; e += 256)
        atomicAdd(&lh[ei[E + e] >> BSH], 1);
    __syncthreads();
    for (int b = threadIdx.x; b < NB; b += 256) hist[b * NBLK_A + blockIdx.x] = lh[b];
}

// generic exclusive scan (3 kernels)
__global__ void scan1(const int* __restrict__ in, int* __restrict__ out,
                      int* __restrict__ bsums, int n) {
    __shared__ int s[1024];
    int i = blockIdx.x * 1024 + threadIdx.x;
    int d = (i < n) ? in[i] : 0;
    s[threadIdx.x] = d;
    __syncthreads();
    for (int off = 1; off < 1024; off <<= 1) {
        int v = (threadIdx.x >= off) ? s[threadIdx.x - off] : 0;
        __syncthreads();
        s[threadIdx.x] += v;
        __syncthreads();
    }
    if (i < n) out[i] = s[threadIdx.x] - d;
    if (threadIdx.x == 1023) bsums[blockIdx.x] = s[1023];
}
__global__ void scan2(int* __restrict__ bsums, int nb) {
    __shared__ int s[128];
    int v = (threadIdx.x < nb) ? bsums[threadIdx.x] : 0;
    s[threadIdx.x] = v;
    __syncthreads();
    for (int off = 1; off < 128; off <<= 1) {
        int u = (threadIdx.x >= off) ? s[threadIdx.x - off] : 0;
        __syncthreads();
        s[threadIdx.x] += u;
        __syncthreads();
    }
    if (threadIdx.x < nb) bsums[threadIdx.x] = s[threadIdx.x] - v;
}
__global__ void scan3(int* __restrict__ out, const int* __restrict__ bsums, int n) {
    int i = blockIdx.x * 1024 + threadIdx.x;
    if (i < n) out[i] += bsums[blockIdx.x];
}

// ---------------------------------------------------------------------------
// K5 (pass A1): place edges into dst-buckets. staged = dloc<<19 | rel<<17 | src
// ---------------------------------------------------------------------------
__global__ void __launch_bounds__(256) place_kernel(const int* __restrict__ ei, const int* __restrict__ et,
                                                    const int* __restrict__ off, unsigned* __restrict__ staged,
                                                    int E, int NB, int chunk) {
    __shared__ int lh[256];
    for (int t = threadIdx.x; t < NB; t += 256) lh[t] = 0;
    __syncthreads();
    int s = blockIdx.x * chunk, e1 = min(E, s + chunk);
    for (int e = s + threadIdx.x; e < e1; e += 256) {
        int d = ei[E + e];
        int b = d >> BSH;
        int lr = atomicAdd(&lh[b], 1);
        int pos = off[b * NBLK_A + blockIdx.x] + lr;
        staged[pos] = ((unsigned)(d & (BNODES - 1)) << 19) | ((unsigned)et[e] << 17) | (unsigned)ei[e];
    }
}

// ---------------------------------------------------------------------------
// K6 (pass B): finalize into whole-node x4-padded CSR with per-edge
// precomputed weight w = 1/cnt(dst,rel).
//   edges2[e] = { (rel*N+src)*16 (uint2 row offset into Y), asu(w) }
//   edges1[e] = f2bf(w)<<16 | rel<<6 | combo(src)      (pads: all zero)
//   base1[i], plen[i] (padded length, multiple of 4)
// Bucket capacity = raw + 3*BNODES.
// ---------------------------------------------------------------------------
__global__ void __launch_bounds__(256) finalize_kernel(
        const unsigned* __restrict__ staged, const int* __restrict__ off,
        const unsigned char* __restrict__ combo,
        unsigned* __restrict__ edges1, uint2* __restrict__ edges2,
        int* __restrict__ base1, unsigned short* __restrict__ plen,
        int E, int N, int NB) {
    __shared__ int lrel[BNODES * 3];   // per-(node,rel) counts (stay counts)
    __shared__ float lwf[BNODES * 3];  // 1/count
    __shared__ int lcnt[BNODES];       // placement cursors
    __shared__ int part[256];
    int blk = blockIdx.x;
    int d0 = blk * BNODES;
    int nn = min(BNODES, N - d0);
    int estart = off[blk * NBLK_A];
    int eend = (blk == NB - 1) ? E : off[(blk + 1) * NBLK_A];
    int ebase = estart + blk * (BNODES * 3);   // padded-capacity base
    for (int t = threadIdx.x; t < BNODES * 3; t += 256) lrel[t] = 0;
    __syncthreads();
    for (int e = estart + threadIdx.x; e < eend; e += 256) {
        unsigned p = staged[e];
        atomicAdd(&lrel[(p >> 19) * 3 + ((p >> 17) & 3)], 1);
    }
    __syncthreads();
    for (int j = threadIdx.x; j < BNODES * 3; j += 256) {
        int c = lrel[j];
        lwf[j] = c ? 1.f / (float)c : 0.f;
    }
    // padded exclusive scan over whole-node lengths (2 nodes/thread)
    int t = threadIdx.x;
    int n0 = 2 * t, n1 = 2 * t + 1;
    int ct0 = lrel[n0 * 3] + lrel[n0 * 3 + 1] + lrel[n0 * 3 + 2];
    int ct1 = lrel[n1 * 3] + lrel[n1 * 3 + 1] + lrel[n1 * 3 + 2];
    int pl0 = (ct0 + 3) & ~3, pl1 = (ct1 + 3) & ~3;
    int sum = pl0 + pl1;
    part[t] = sum;
    __syncthreads();
    for (int o = 1; o < 256; o <<= 1) {
        int u = (t >= o) ? part[t - o] : 0;
        __syncthreads();
        part[t] += u;
        __syncthreads();
    }
    int run = ebase + part[t] - sum;
    lcnt[n0] = run;
    lcnt[n1] = run + pl0;
    if (n0 < nn) { base1[d0 + n0] = run;       plen[d0 + n0] = (unsigned short)pl0; }
    if (n1 < nn) { base1[d0 + n1] = run + pl0; plen[d0 + n1] = (unsigned short)pl1; }
    __syncthreads();
    for (int e = estart + threadIdx.x; e < eend; e += 256) {
        unsigned p = staged[e];
        int dloc = p >> 19;
        unsigned rel = (p >> 17) & 3;
        unsigned src = p & 0x1FFFF;
        float w = lwf[dloc * 3 + rel];
        int slot = atomicAdd(&lcnt[dloc], 1);
        uint2 e2;
        e2.x = (rel * (unsigned)N + src) * 16u;
        e2.y = asu(w);
        edges2[slot] = e2;
        edges1[slot] = (f2bf(w) << 16) | (rel << 6) | (unsigned)combo[src];
    }
    __syncthreads();
    for (int n = threadIdx.x; n < nn; n += 256) {
        int ct = lrel[n * 3] + lrel[n * 3 + 1] + lrel[n * 3 + 2];
        int need = ((ct + 3) & ~3) - ct;          // 0..3 pads, w = 0
        int cur = lcnt[n];
        for (int k = 0; k < need; ++k) {
            uint2 z; z.x = 0u; z.y = 0u;
            edges2[cur + k] = z;
            edges1[cur + k] = 0u;
        }
    }
}

// ---------------------------------------------------------------------------
// K7: fused conv1 = root-table + weighted table-gather, relu -> h1 bf16.
// Grid-stride persistent blocks (fill 24KB LDS table once per block).
// HALF-WAVE per edge: 32 lanes x 1 dword each cover one 128B table row ->
// bank d gets exactly 2 lanes (the two halves) = conflict-free (2-way free).
// ---------------------------------------------------------------------------
__global__ void __launch_bounds__(256) conv1_gather(
        const unsigned* __restrict__ edges1, const int* __restrict__ base1,
        const unsigned short* __restrict__ plen, const unsigned short* __restrict__ msg1t,
        const float* __restrict__ root1t, const unsigned char* __restrict__ combo,
        unsigned* __restrict__ h1u, int N, int nGrp) {
    __shared__ unsigned tab[192 * 32];     // rows of 32 dwords (64 bf16)
    const unsigned* m4 = (const unsigned*)msg1t;
    for (int t = threadIdx.x; t < 192 * 32; t += 256) tab[t] = m4[t];
    __syncthreads();
    int lane = threadIdx.x & 63;
    int w = threadIdx.x >> 6;
    int d = lane & 31, half = lane >> 5;
    for (int g = blockIdx.x; g < nGrp; g += gridDim.x) {
        int i = g * 4 + w;
        if (i >= N) continue;
        int s = base1[i];
        int L = plen[i];
        float f0 = 0.f, f1 = 0.f;
        for (int t2 = 0; t2 < L; t2 += 2) {
            unsigned ew = edges1[s + t2 + half];
            float wt = asf(ew & 0xFFFF0000u);          // bf16 weight in high bits
            unsigned m = tab[(ew & 255u) * 32 + d];
            f0 = fmaf(wt, asf(m << 16), f0);
            f1 = fmaf(wt, asf(m & 0xFFFF0000u), f1);
        }
        f0 += __shfl_xor(f0, 32);
        f1 += __shfl_xor(f1, 32);
        if (half == 0) {
            const float2 rt = *(const float2*)&root1t[(int)combo[i] * 64 + 2 * d];
            float v0 = f0 + rt.x; v0 = v0 > 0.f ? v0 : 0.f;
            float v1 = f1 + rt.y; v1 = v1 > 0.f ? v1 : 0.f;
            h1u[(size_t)i * 32 + d] = f2bf(v0) | (f2bf(v1) << 16);
        }
    }
}

// ---------------------------------------------------------------------------
// K8: gemm_Y. [16,64]@[64,256] MFMA per wave: cols 0..63 -> R = h1@root2+b2,
// cols 64..255 -> Y_r = h1@W2_r. All bf16 out.
// ---------------------------------------------------------------------------
__global__ void __launch_bounds__(256) gemm_Y(
        const unsigned short* __restrict__ h1, const unsigned short* __restrict__ B2f,
        const float* __restrict__ b2, unsigned short* __restrict__ Rb,
        unsigned short* __restrict__ Y, int N) {
    int g = blockIdx.x * 4 + (threadIdx.x >> 6);
    int node0 = g * 16;
    if (node0 >= N) return;
    int lane = threadIdx.x & 63;
    int m = lane & 15, kg = lane >> 4;
    short8 a[2];
#pragma unroll
    for (int kt = 0; kt < 2; ++kt)
        a[kt] = *(const short8*)(h1 + (size_t)(node0 + m) * 64 + kt * 32 + kg * 8);
#pragma unroll
    for (int nt = 0; nt < 16; ++nt) {
        floatx4 c = {0.f, 0.f, 0.f, 0.f};
#pragma unroll
        for (int kt = 0; kt < 2; ++kt) {
            short8 b = *(const short8*)(B2f + ((nt * 2 + kt) * 64 + lane) * 8);
            c = __builtin_amdgcn_mfma_f32_16x16x32_bf16(a[kt], b, c, 0, 0, 0);
        }
        if (nt < 4) {
            int col = nt * 16 + m;
            float bias = b2[col];
#pragma unroll
            for (int q = 0; q < 4; ++q) {
                int node = node0 + kg * 4 + q;
                if (node < N) Rb[(size_t)node * 64 + col] = (unsigned short)f2bf(c[q] + bias);
            }
        } else {
            int r = (nt - 4) >> 2;
            int ycol = ((nt - 4) & 3) * 16 + m;
#pragma unroll
            for (int q = 0; q < 4; ++q) {
                int node = node0 + kg * 4 + q;
                if (node < N)
                    Y[((size_t)r * N + node) * 64 + ycol] = (unsigned short)f2bf(c[q]);
            }
        }
    }
}

// ---------------------------------------------------------------------------
// K9: conv2 gather. Wave per node; quarter-wave per edge, single weighted
// accumulator (rel folded into the Y offset + weight). h2 = R + sum (pre-relu).
// ---------------------------------------------------------------------------
__global__ void __launch_bounds__(256) conv2_gather(
        const uint2* __restrict__ edges2, const int* __restrict__ base1,
        const unsigned short* __restrict__ plen, const uint2* __restrict__ Yu2,
        const uint2* __restrict__ Ru2, uint2* __restrict__ h2u2, int N) {
    int i = blockIdx.x * 4 + (threadIdx.x >> 6);
    if (i >= N) return;
    int lane = threadIdx.x & 63;
    int l16 = lane & 15, q = lane >> 4;
    int s = base1[i];
    int L = plen[i];
    float f0 = 0.f, f1 = 0.f, f2 = 0.f, f3 = 0.f;
    for (int t2 = 0; t2 < L; t2 += 4) {
        uint2 e = edges2[s + t2 + q];
        float wt = asf(e.y);
        uint2 v = Yu2[(size_t)e.x + l16];
        f0 = fmaf(wt, asf(v.x << 16), f0);
        f1 = fmaf(wt, asf(v.x & 0xFFFF0000u), f1);
        f2 = fmaf(wt, asf(v.y << 16), f2);
        f3 = fmaf(wt, asf(v.y & 0xFFFF0000u), f3);
    }
    f0 += __shfl_xor(f0, 16); f0 += __shfl_xor(f0, 32);
    f1 += __shfl_xor(f1, 16); f1 += __shfl_xor(f1, 32);
    f2 += __shfl_xor(f2, 16); f2 += __shfl_xor(f2, 32);
    f3 += __shfl_xor(f3, 16); f3 += __shfl_xor(f3, 32);
    if (q == 0) {
        uint2 rb = Ru2[(size_t)i * 16 + l16];
        f0 += asf(rb.x << 16);
        f1 += asf(rb.x & 0xFFFF0000u);
        f2 += asf(rb.y << 16);
        f3 += asf(rb.y & 0xFFFF0000u);
        uint2 o;
        o.x = f2bf(f0) | (f2bf(f1) << 16);
        o.y = f2bf(f2) | (f2bf(f3) << 16);
        h2u2[(size_t)i * 16 + l16] = o;
    }
}

// ---------------------------------------------------------------------------
// K10: mean-pool (sorted batch -> binary search) + classifier; relu folded.
// ---------------------------------------------------------------------------
__global__ void __launch_bounds__(64) pool_cls(
        const unsigned short* __restrict__ h2, const int* __restrict__ batch,
        const float* __restrict__ cls_w, const float* __restrict__ cls_b,
        float* __restrict__ out, int N, int G) {
    int g = blockIdx.x, lane = threadIdx.x;
    auto lb = [&](int key) {
        int lo = 0, hi = N;
        while (lo < hi) { int mid = (lo + hi) >> 1; if (batch[mid] < key) lo = mid + 1; else hi = mid; }
        return lo;
    };
    int start = lb(g), end = lb(g + 1);
    float sum = 0.f;
    for (int i = start; i < end; ++i) {
        float v = bf2f(h2[(size_t)i * 64 + lane]);
        sum += v > 0.f ? v : 0.f;
    }
    int cntn = end - start;
    float pooled = sum / (float)(cntn > 0 ? cntn : 1);
    __shared__ float ps[64];
    ps[lane] = pooled;
    __syncthreads();
    if (lane < 10) {
        float o = cls_b[lane];
#pragma unroll
        for (int j = 0; j < 64; ++j) o = fmaf(ps[j], cls_w[j * 10 + lane], o);
        out[g * 10 + lane] = o;
    }
}

// ---------------------------------------------------------------------------
extern "C" void kernel_launch(void* const* d_in, const int* in_sizes, int n_in,
                              void* d_out, int out_size, void* d_ws, size_t ws_size,
                              hipStream_t stream) {
    const int*   node_x = (const int*)d_in[0];
    const int*   ei     = (const int*)d_in[1];
    const int*   et     = (const int*)d_in[2];
    const int*   batch  = (const int*)d_in[3];
    const float* pre_w  = (const float*)d_in[4];
    const float* pre_b  = (const float*)d_in[5];
    const float* w1     = (const float*)d_in[6];
    const float* root1  = (const float*)d_in[7];
    const float* b1     = (const float*)d_in[8];
    const float* w2     = (const float*)d_in[9];
    const float* root2  = (const float*)d_in[10];
    const float* b2     = (const float*)d_in[11];
    const float* cls_w  = (const float*)d_in[12];
    const float* cls_b  = (const float*)d_in[13];
    float* out = (float*)d_out;

    int N = in_sizes[0] / 2;
    int E = in_sizes[1] / 2;
    int G = out_size / 10;

    int NB = (N + BNODES - 1) >> BSH;
    int chunk = (E + NBLK_A - 1) / NBLK_A;
    int nh = NB * NBLK_A;
    int nscan = (nh + 1023) / 1024;
    int EP = E + NB * BNODES * 3;      // whole-node pads (<=3/node)

    char* ws = (char*)d_ws;
    size_t off_b = 0;
    auto alloc = [&](size_t bytes) {
        void* p = ws + off_b;
        off_b = (off_b + bytes + 255) & ~(size_t)255;
        return p;
    };
    unsigned short* msg1t  = (unsigned short*)alloc(192 * 64 * sizeof(short));
    float*          root1t = (float*)alloc(64 * 64 * sizeof(float));
    unsigned short* B2f    = (unsigned short*)alloc(16 * 2 * 64 * 8 * sizeof(short));
    unsigned char*  combo  = (unsigned char*)alloc((size_t)N + 64);
    int*            hist   = (int*)alloc((size_t)nh * sizeof(int));
    int*            hoff   = (int*)alloc((size_t)nh * sizeof(int));
    int*            bsums  = (int*)alloc(128 * sizeof(int));
    unsigned*       staged = (unsigned*)alloc((size_t)E * sizeof(unsigned));
    unsigned*       edges1 = (unsigned*)alloc((size_t)EP * sizeof(unsigned));
    uint2*          edges2 = (uint2*)alloc((size_t)EP * sizeof(uint2));
    int*            base1  = (int*)alloc(((size_t)N + 8) * sizeof(int));
    unsigned short* plen   = (unsigned short*)alloc(((size_t)N + 8) * sizeof(short));
    unsigned short* h1     = (unsigned short*)alloc((size_t)(N + 16) * 64 * sizeof(short));
    unsigned short* Rb     = (unsigned short*)alloc((size_t)N * 64 * sizeof(short));
    unsigned short* Y      = (unsigned short*)alloc((size_t)3 * N * 64 * sizeof(short));
    unsigned short* h2     = (unsigned short*)alloc((size_t)N * 64 * sizeof(short));

    build_tables<<<64, 64, 0, stream>>>(pre_w, pre_b, w1, root1, b1, msg1t, root1t);
    prep_B2<<<64, 256, 0, stream>>>(root2, w2, B2f);
    combo_kernel<<<(N + 255) / 256, 256, 0, stream>>>(node_x, combo, N);

    hist_kernel<<<NBLK_A, 256, 0, stream>>>(ei, hist, E, NB, chunk);
    scan1<<<nscan, 1024, 0, stream>>>(hist, hoff, bsums, nh);
    scan2<<<1, 128, 0, stream>>>(bsums, nscan);
    scan3<<<nscan, 1024, 0, stream>>>(hoff, bsums, nh);
    place_kernel<<<NBLK_A, 256, 0, stream>>>(ei, et, hoff, staged, E, NB, chunk);
    finalize_kernel<<<NB, 256, 0, stream>>>(staged, hoff, combo, edges1, edges2,
                                            base1, plen, E, N, NB);

    int nGrp = (N + 3) / 4;
    conv1_gather<<<2048, 256, 0, stream>>>(edges1, base1, plen, msg1t, root1t,
                                           combo, (unsigned*)h1, N, nGrp);
    gemm_Y<<<((N + 15) / 16 + 3) / 4, 256, 0, stream>>>(h1, B2f, b2, Rb, Y, N);
    conv2_gather<<<(N + 3) / 4, 256, 0, stream>>>(edges2, base1, plen, (const uint2*)Y,
                                                  (const uint2*)Rb, (uint2*)h2, N);
    pool_cls<<<G, 64, 0, stream>>>(h2, batch, cls_w, cls_b, out, N, G);
}

// Round 12
// 222.835 us; speedup vs baseline: 1.2674x; 1.1690x over previous
//
#include <hip/hip_runtime.h>

#define BSH 9              // 512 nodes per dst bucket
#define BNODES 512
#define NBLK_A 256         // blocks in hist/place passes

typedef __attribute__((ext_vector_type(8))) short short8;
typedef __attribute__((ext_vector_type(4))) float floatx4;

static __device__ inline float bf2f(unsigned short u) {
    union { unsigned int i; float f; } v; v.i = ((unsigned int)u) << 16; return v.f;
}
static __device__ inline unsigned f2bf(float f) {
    union { float f; unsigned int i; } v; v.f = f;
    unsigned int x = v.i;
    return (x + 0x7FFF + ((x >> 16) & 1)) >> 16;  // RNE
}
static __device__ inline float asf(unsigned int u) {
    union { unsigned int i; float f; } v; v.i = u; return v.f;
}
static __device__ inline unsigned asu(float f) {
    union { float f; unsigned int i; } v; v.f = f; return v.i;
}

// ---------------------------------------------------------------------------
// K1: tables. root1t[64][64] f32; msg (= x1 @ W1_r, [192][64] bf16) written
// DIRECTLY in MFMA B-fragment layout:
//   B1f[((nt*6+kt)*64 + l)*8 + i] = msg[kt*32 + (l>>4)*8 + i][nt*16 + (l&15)]
// ---------------------------------------------------------------------------
__global__ void build_tables(const float* __restrict__ pre_w, const float* __restrict__ pre_b,
                             const float* __restrict__ w1, const float* __restrict__ root1,
                             const float* __restrict__ b1,
                             unsigned short* __restrict__ B1f, float* __restrict__ root1t) {
    int combo = blockIdx.x, j = threadIdx.x;
    __shared__ float x1s[32];
    int s = combo >> 3, c = combo & 7;
    if (j < 32) {
        float v = pre_w[s * 32 + j] + pre_w[(8 + c) * 32 + j] + pre_b[j];
        x1s[j] = v > 0.f ? v : 0.f;
    }
    __syncthreads();
    float acc = b1[j];
#pragma unroll
    for (int k = 0; k < 32; ++k) acc = fmaf(x1s[k], root1[k * 64 + j], acc);
    root1t[combo * 64 + j] = acc;
    for (int r = 0; r < 3; ++r) {
        float a = 0.f;
#pragma unroll
        for (int k = 0; k < 32; ++k) a = fmaf(x1s[k], w1[(r * 32 + k) * 64 + j], a);
        int idx = (r << 6) | combo;            // B row
        int kt = idx >> 5, i = idx & 7, lrow = (idx >> 3) & 3;
        int nt = j >> 4;
        int l = (lrow << 4) | (j & 15);
        B1f[(((nt * 6 + kt) * 64) + l) * 8 + i] = (unsigned short)f2bf(a);
    }
}

// ---------------------------------------------------------------------------
// K2: B-fragments for the [64,256] matrix [root2 | W2_0 | W2_1 | W2_2].
// ---------------------------------------------------------------------------
__global__ void prep_B2(const float* __restrict__ root2, const float* __restrict__ w2,
                        unsigned short* __restrict__ B2f) {
    int t = blockIdx.x * blockDim.x + threadIdx.x;
    if (t >= 16 * 2 * 64 * 8) return;
    int i = t & 7, l = (t >> 3) & 63, kt = (t >> 9) & 1, nt = t >> 10;
    int k = kt * 32 + ((l >> 4) * 8) + i;
    int col = nt * 16 + (l & 15);
    float v;
    if (col < 64) v = root2[k * 64 + col];
    else {
        int r = (col - 64) >> 6, wcol = (col - 64) & 63;
        v = w2[(r * 64 + k) * 64 + wcol];
    }
    B2f[t] = (unsigned short)f2bf(v);
}

// K3: combo[i] as u8
__global__ void combo_kernel(const int* __restrict__ node_x, unsigned char* __restrict__ combo, int N) {
    int i = blockIdx.x * blockDim.x + threadIdx.x;
    if (i < N) combo[i] = (unsigned char)(node_x[2 * i] * 8 + node_x[2 * i + 1]);
}

// ---------------------------------------------------------------------------
// K4 (pass A0): per-block dst-bucket histogram. hist[b*NBLK_A + blk]
// ---------------------------------------------------------------------------
__global__ void __launch_bounds__(256) hist_kernel(const int* __restrict__ ei,
                                                   int* __restrict__ hist, int E, int NB, int chunk) {
    __shared__ int lh[256];
    for (int t = threadIdx.x; t < NB; t += 256) lh[t] = 0;
    __syncthreads();
    int s = blockIdx.x * chunk, e1 = min(E, s + chunk);
    for (int e = s + threadIdx.x; e < e1; e += 256)
        atomicAdd(&lh[ei[E + e] >> BSH], 1);
    __syncthreads();
    for (int b = threadIdx.x; b < NB; b += 256) hist[b * NBLK_A + blockIdx.x] = lh[b];
}

// generic exclusive scan (3 kernels)
__global__ void scan1(const int* __restrict__ in, int* __restrict__ out,
                      int* __restrict__ bsums, int n) {
    __shared__ int s[1024];
    int i = blockIdx.x * 1024 + threadIdx.x;
    int d = (i < n) ? in[i] : 0;
    s[threadIdx.x] = d;
    __syncthreads();
    for (int off = 1; off < 1024; off <<= 1) {
        int v = (threadIdx.x >= off) ? s[threadIdx.x - off] : 0;
        __syncthreads();
        s[threadIdx.x] += v;
        __syncthreads();
    }
    if (i < n) out[i] = s[threadIdx.x] - d;
    if (threadIdx.x == 1023) bsums[blockIdx.x] = s[1023];
}
__global__ void scan2(int* __restrict__ bsums, int nb) {
    __shared__ int s[128];
    int v = (threadIdx.x < nb) ? bsums[threadIdx.x] : 0;
    s[threadIdx.x] = v;
    __syncthreads();
    for (int off = 1; off < 128; off <<= 1) {
        int u = (threadIdx.x >= off) ? s[threadIdx.x - off] : 0;
        __syncthreads();
        s[threadIdx.x] += u;
        __syncthreads();
    }
    if (threadIdx.x < nb) bsums[threadIdx.x] = s[threadIdx.x] - v;
}
__global__ void scan3(int* __restrict__ out, const int* __restrict__ bsums, int n) {
    int i = blockIdx.x * 1024 + threadIdx.x;
    if (i < n) out[i] += bsums[blockIdx.x];
}

// ---------------------------------------------------------------------------
// K5 (pass A1): place edges into dst-buckets. staged = dloc<<19 | rel<<17 | src
// ---------------------------------------------------------------------------
__global__ void __launch_bounds__(256) place_kernel(const int* __restrict__ ei, const int* __restrict__ et,
                                                    const int* __restrict__ off, unsigned* __restrict__ staged,
                                                    int E, int NB, int chunk) {
    __shared__ int lh[256];
    for (int t = threadIdx.x; t < NB; t += 256) lh[t] = 0;
    __syncthreads();
    int s = blockIdx.x * chunk, e1 = min(E, s + chunk);
    for (int e = s + threadIdx.x; e < e1; e += 256) {
        int d = ei[E + e];
        int b = d >> BSH;
        int lr = atomicAdd(&lh[b], 1);
        int pos = off[b * NBLK_A + blockIdx.x] + lr;
        staged[pos] = ((unsigned)(d & (BNODES - 1)) << 19) | ((unsigned)et[e] << 17) | (unsigned)ei[e];
    }
}

// ---------------------------------------------------------------------------
// K6 (pass B): finalize into whole-node x4-padded CSR with per-edge
// precomputed weight w = 1/cnt(dst,rel).
//   edges2[e] = { (rel*N+src)*16 (uint2 row offset into Y), asu(w) }
//   edges1[e] = f2bf(w)<<16 | (node%64)<<8 | (rel*64+combo)   (pads: 0)
//   base1[i], plen[i]; sentinel base1[N] = end of padded edge array
// Bucket capacity = raw + 3*BNODES.
// ---------------------------------------------------------------------------
__global__ void __launch_bounds__(256) finalize_kernel(
        const unsigned* __restrict__ staged, const int* __restrict__ off,
        const unsigned char* __restrict__ combo,
        unsigned* __restrict__ edges1, uint2* __restrict__ edges2,
        int* __restrict__ base1, unsigned short* __restrict__ plen,
        int E, int N, int NB) {
    __shared__ int lrel[BNODES * 3];   // per-(node,rel) counts (stay counts)
    __shared__ float lwf[BNODES * 3];  // 1/count
    __shared__ int lcnt[BNODES];       // placement cursors
    __shared__ int part[256];
    int blk = blockIdx.x;
    int d0 = blk * BNODES;
    int nn = min(BNODES, N - d0);
    int estart = off[blk * NBLK_A];
    int eend = (blk == NB - 1) ? E : off[(blk + 1) * NBLK_A];
    int ebase = estart + blk * (BNODES * 3);   // padded-capacity base
    for (int t = threadIdx.x; t < BNODES * 3; t += 256) lrel[t] = 0;
    __syncthreads();
    for (int e = estart + threadIdx.x; e < eend; e += 256) {
        unsigned p = staged[e];
        atomicAdd(&lrel[(p >> 19) * 3 + ((p >> 17) & 3)], 1);
    }
    __syncthreads();
    for (int j = threadIdx.x; j < BNODES * 3; j += 256) {
        int c = lrel[j];
        lwf[j] = c ? 1.f / (float)c : 0.f;
    }
    // padded exclusive scan over whole-node lengths (2 nodes/thread)
    int t = threadIdx.x;
    int n0 = 2 * t, n1 = 2 * t + 1;
    int ct0 = lrel[n0 * 3] + lrel[n0 * 3 + 1] + lrel[n0 * 3 + 2];
    int ct1 = lrel[n1 * 3] + lrel[n1 * 3 + 1] + lrel[n1 * 3 + 2];
    int pl0 = (ct0 + 3) & ~3, pl1 = (ct1 + 3) & ~3;
    int sum = pl0 + pl1;
    part[t] = sum;
    __syncthreads();
    for (int o = 1; o < 256; o <<= 1) {
        int u = (t >= o) ? part[t - o] : 0;
        __syncthreads();
        part[t] += u;
        __syncthreads();
    }
    int run = ebase + part[t] - sum;
    lcnt[n0] = run;
    lcnt[n1] = run + pl0;
    if (n0 < nn) { base1[d0 + n0] = run;       plen[d0 + n0] = (unsigned short)pl0; }
    if (n1 < nn) { base1[d0 + n1] = run + pl0; plen[d0 + n1] = (unsigned short)pl1; }
    if (blk == NB - 1 && t == 255) base1[N] = ebase + part[255];   // sentinel
    __syncthreads();
    for (int e = estart + threadIdx.x; e < eend; e += 256) {
        unsigned p = staged[e];
        int dloc = p >> 19;
        unsigned rel = (p >> 17) & 3;
        unsigned src = p & 0x1FFFF;
        float w = lwf[dloc * 3 + rel];
        int slot = atomicAdd(&lcnt[dloc], 1);
        uint2 e2;
        e2.x = (rel * (unsigned)N + src) * 16u;
        e2.y = asu(w);
        edges2[slot] = e2;
        edges1[slot] = (f2bf(w) << 16) | ((unsigned)(dloc & 63) << 8)
                     | (rel << 6) | (unsigned)combo[src];
    }
    __syncthreads();
    for (int n = threadIdx.x; n < nn; n += 256) {
        int ct = lrel[n * 3] + lrel[n * 3 + 1] + lrel[n * 3 + 2];
        int need = ((ct + 3) & ~3) - ct;          // 0..3 pads, w = 0
        int cur = lcnt[n];
        for (int k = 0; k < need; ++k) {
            uint2 z; z.x = 0u; z.y = 0u;
            edges2[cur + k] = z;
            edges1[cur + k] = 0u;        // w=0 -> contributes nothing
        }
    }
}

// ---------------------------------------------------------------------------
// K7: conv1 as count-matrix MFMA. Block = 64 nodes.
// Phase 1 (streaming): C[nl][idx] += w  for each edge word (LDS f32 atomics,
//   coalesced edge loads, no dependent chains, no per-node loops).
// Phase 2: AGG = C @ msg (MFMA, K=192), + root1t[combo], relu -> h1 bf16.
// C rows padded to 196 f32 (bank stride 4 -> 2-way access, free).
// ---------------------------------------------------------------------------
#define CSTR 196
__global__ void __launch_bounds__(256) conv1_mfma(
        const unsigned* __restrict__ edges1, const int* __restrict__ base1,
        const unsigned short* __restrict__ B1f, const float* __restrict__ root1t,
        const unsigned char* __restrict__ combo, unsigned short* __restrict__ h1, int N) {
    __shared__ float Cs[64 * CSTR];
    for (int t = threadIdx.x; t < 64 * CSTR; t += 256) Cs[t] = 0.f;
    __syncthreads();
    int g0 = blockIdx.x * 64;
    int gEnd = min(g0 + 64, N);
    int estart = base1[g0], eend = base1[gEnd];
    for (int e = estart + threadIdx.x; e < eend; e += 256) {
        unsigned ew = edges1[e];
        float wt = asf(ew & 0xFFFF0000u);        // bf16 weight in high bits
        int nl = (ew >> 8) & 63;
        int idx = ew & 255u;
        atomicAdd(&Cs[nl * CSTR + idx], wt);
    }
    __syncthreads();
    int lane = threadIdx.x & 63;
    int w0 = threadIdx.x >> 6;
    int node0 = g0 + 16 * w0;
    if (node0 >= N) return;
    int m = lane & 15, kg = lane >> 4;
    const float* cr = &Cs[(16 * w0 + m) * CSTR];
    short8 a[6];
#pragma unroll
    for (int kt = 0; kt < 6; ++kt) {
        float4 ca = *(const float4*)(cr + kt * 32 + kg * 8);
        float4 cb = *(const float4*)(cr + kt * 32 + kg * 8 + 4);
        short8 av;
        av[0] = (short)f2bf(ca.x); av[1] = (short)f2bf(ca.y);
        av[2] = (short)f2bf(ca.z); av[3] = (short)f2bf(ca.w);
        av[4] = (short)f2bf(cb.x); av[5] = (short)f2bf(cb.y);
        av[6] = (short)f2bf(cb.z); av[7] = (short)f2bf(cb.w);
        a[kt] = av;
    }
#pragma unroll
    for (int nt = 0; nt < 4; ++nt) {
        floatx4 c = {0.f, 0.f, 0.f, 0.f};
#pragma unroll
        for (int kt = 0; kt < 6; ++kt) {
            short8 b = *(const short8*)(B1f + ((nt * 6 + kt) * 64 + lane) * 8);
            c = __builtin_amdgcn_mfma_f32_16x16x32_bf16(a[kt], b, c, 0, 0, 0);
        }
#pragma unroll
        for (int q = 0; q < 4; ++q) {
            int node = node0 + kg * 4 + q;
            if (node < N) {
                float v = c[q] + root1t[(int)combo[node] * 64 + nt * 16 + m];
                v = v > 0.f ? v : 0.f;
                h1[(size_t)node * 64 + nt * 16 + m] = (unsigned short)f2bf(v);
            }
        }
    }
}

// ---------------------------------------------------------------------------
// K8: gemm_Y. [16,64]@[64,256] MFMA per wave: cols 0..63 -> R = h1@root2+b2,
// cols 64..255 -> Y_r = h1@W2_r. All bf16 out.
// ---------------------------------------------------------------------------
__global__ void __launch_bounds__(256) gemm_Y(
        const unsigned short* __restrict__ h1, const unsigned short* __restrict__ B2f,
        const float* __restrict__ b2, unsigned short* __restrict__ Rb,
        unsigned short* __restrict__ Y, int N) {
    int g = blockIdx.x * 4 + (threadIdx.x >> 6);
    int node0 = g * 16;
    if (node0 >= N) return;
    int lane = threadIdx.x & 63;
    int m = lane & 15, kg = lane >> 4;
    short8 a[2];
#pragma unroll
    for (int kt = 0; kt < 2; ++kt)
        a[kt] = *(const short8*)(h1 + (size_t)(node0 + m) * 64 + kt * 32 + kg * 8);
#pragma unroll
    for (int nt = 0; nt < 16; ++nt) {
        floatx4 c = {0.f, 0.f, 0.f, 0.f};
#pragma unroll
        for (int kt = 0; kt < 2; ++kt) {
            short8 b = *(const short8*)(B2f + ((nt * 2 + kt) * 64 + lane) * 8);
            c = __builtin_amdgcn_mfma_f32_16x16x32_bf16(a[kt], b, c, 0, 0, 0);
        }
        if (nt < 4) {
            int col = nt * 16 + m;
            float bias = b2[col];
#pragma unroll
            for (int q = 0; q < 4; ++q) {
                int node = node0 + kg * 4 + q;
                if (node < N) Rb[(size_t)node * 64 + col] = (unsigned short)f2bf(c[q] + bias);
            }
        } else {
            int r = (nt - 4) >> 2;
            int ycol = ((nt - 4) & 3) * 16 + m;
#pragma unroll
            for (int q = 0; q < 4; ++q) {
                int node = node0 + kg * 4 + q;
                if (node < N)
                    Y[((size_t)r * N + node) * 64 + ycol] = (unsigned short)f2bf(c[q]);
            }
        }
    }
}

// ---------------------------------------------------------------------------
// K9: conv2 gather. Wave per node; quarter-wave per edge, single weighted
// accumulator (rel folded into the Y offset + weight). h2 = R + sum (pre-relu).
// ---------------------------------------------------------------------------
__global__ void __launch_bounds__(256) conv2_gather(
        const uint2* __restrict__ edges2, const int* __restrict__ base1,
        const unsigned short* __restrict__ plen, const uint2* __restrict__ Yu2,
        const uint2* __restrict__ Ru2, uint2* __restrict__ h2u2, int N) {
    int i = blockIdx.x * 4 + (threadIdx.x >> 6);
    if (i >= N) return;
    int lane = threadIdx.x & 63;
    int l16 = lane & 15, q = lane >> 4;
    int s = base1[i];
    int L = plen[i];
    float f0 = 0.f, f1 = 0.f, f2 = 0.f, f3 = 0.f;
    for (int t2 = 0; t2 < L; t2 += 4) {
        uint2 e = edges2[s + t2 + q];
        float wt = asf(e.y);
        uint2 v = Yu2[(size_t)e.x + l16];
        f0 = fmaf(wt, asf(v.x << 16), f0);
        f1 = fmaf(wt, asf(v.x & 0xFFFF0000u), f1);
        f2 = fmaf(wt, asf(v.y << 16), f2);
        f3 = fmaf(wt, asf(v.y & 0xFFFF0000u), f3);
    }
    f0 += __shfl_xor(f0, 16); f0 += __shfl_xor(f0, 32);
    f1 += __shfl_xor(f1, 16); f1 += __shfl_xor(f1, 32);
    f2 += __shfl_xor(f2, 16); f2 += __shfl_xor(f2, 32);
    f3 += __shfl_xor(f3, 16); f3 += __shfl_xor(f3, 32);
    if (q == 0) {
        uint2 rb = Ru2[(size_t)i * 16 + l16];
        f0 += asf(rb.x << 16);
        f1 += asf(rb.x & 0xFFFF0000u);
        f2 += asf(rb.y << 16);
        f3 += asf(rb.y & 0xFFFF0000u);
        uint2 o;
        o.x = f2bf(f0) | (f2bf(f1) << 16);
        o.y = f2bf(f2) | (f2bf(f3) << 16);
        h2u2[(size_t)i * 16 + l16] = o;
    }
}

// ---------------------------------------------------------------------------
// K10: mean-pool (sorted batch -> binary search) + classifier; relu folded.
// ---------------------------------------------------------------------------
__global__ void __launch_bounds__(64) pool_cls(
        const unsigned short* __restrict__ h2, const int* __restrict__ batch,
        const float* __restrict__ cls_w, const float* __restrict__ cls_b,
        float* __restrict__ out, int N, int G) {
    int g = blockIdx.x, lane = threadIdx.x;
    auto lb = [&](int key) {
        int lo = 0, hi = N;
        while (lo < hi) { int mid = (lo + hi) >> 1; if (batch[mid] < key) lo = mid + 1; else hi = mid; }
        return lo;
    };
    int start = lb(g), end = lb(g + 1);
    float sum = 0.f;
    for (int i = start; i < end; ++i) {
        float v = bf2f(h2[(size_t)i * 64 + lane]);
        sum += v > 0.f ? v : 0.f;
    }
    int cntn = end - start;
    float pooled = sum / (float)(cntn > 0 ? cntn : 1);
    __shared__ float ps[64];
    ps[lane] = pooled;
    __syncthreads();
    if (lane < 10) {
        float o = cls_b[lane];
#pragma unroll
        for (int j = 0; j < 64; ++j) o = fmaf(ps[j], cls_w[j * 10 + lane], o);
        out[g * 10 + lane] = o;
    }
}

// ---------------------------------------------------------------------------
extern "C" void kernel_launch(void* const* d_in, const int* in_sizes, int n_in,
                              void* d_out, int out_size, void* d_ws, size_t ws_size,
                              hipStream_t stream) {
    const int*   node_x = (const int*)d_in[0];
    const int*   ei     = (const int*)d_in[1];
    const int*   et     = (const int*)d_in[2];
    const int*   batch  = (const int*)d_in[3];
    const float* pre_w  = (const float*)d_in[4];
    const float* pre_b  = (const float*)d_in[5];
    const float* w1     = (const float*)d_in[6];
    const float* root1  = (const float*)d_in[7];
    const float* b1     = (const float*)d_in[8];
    const float* w2     = (const float*)d_in[9];
    const float* root2  = (const float*)d_in[10];
    const float* b2     = (const float*)d_in[11];
    const float* cls_w  = (const float*)d_in[12];
    const float* cls_b  = (const float*)d_in[13];
    float* out = (float*)d_out;

    int N = in_sizes[0] / 2;
    int E = in_sizes[1] / 2;
    int G = out_size / 10;

    int NB = (N + BNODES - 1) >> BSH;
    int chunk = (E + NBLK_A - 1) / NBLK_A;
    int nh = NB * NBLK_A;
    int nscan = (nh + 1023) / 1024;
    int EP = E + NB * BNODES * 3;      // whole-node pads (<=3/node)

    char* ws = (char*)d_ws;
    size_t off_b = 0;
    auto alloc = [&](size_t bytes) {
        void* p = ws + off_b;
        off_b = (off_b + bytes + 255) & ~(size_t)255;
        return p;
    };
    unsigned short* B1f    = (unsigned short*)alloc(4 * 6 * 64 * 8 * sizeof(short));
    float*          root1t = (float*)alloc(64 * 64 * sizeof(float));
    unsigned short* B2f    = (unsigned short*)alloc(16 * 2 * 64 * 8 * sizeof(short));
    unsigned char*  combo  = (unsigned char*)alloc((size_t)N + 64);
    int*            hist   = (int*)alloc((size_t)nh * sizeof(int));
    int*            hoff   = (int*)alloc((size_t)nh * sizeof(int));
    int*            bsums  = (int*)alloc(128 * sizeof(int));
    unsigned*       staged = (unsigned*)alloc((size_t)E * sizeof(unsigned));
    unsigned*       edges1 = (unsigned*)alloc((size_t)EP * sizeof(unsigned));
    uint2*          edges2 = (uint2*)alloc((size_t)EP * sizeof(uint2));
    int*            base1  = (int*)alloc(((size_t)N + 8) * sizeof(int));
    unsigned short* plen   = (unsigned short*)alloc(((size_t)N + 8) * sizeof(short));
    unsigned short* h1     = (unsigned short*)alloc((size_t)(N + 16) * 64 * sizeof(short));
    unsigned short* Rb     = (unsigned short*)alloc((size_t)N * 64 * sizeof(short));
    unsigned short* Y      = (unsigned short*)alloc((size_t)3 * N * 64 * sizeof(short));
    unsigned short* h2     = (unsigned short*)alloc((size_t)N * 64 * sizeof(short));

    build_tables<<<64, 64, 0, stream>>>(pre_w, pre_b, w1, root1, b1, B1f, root1t);
    prep_B2<<<64, 256, 0, stream>>>(root2, w2, B2f);
    combo_kernel<<<(N + 255) / 256, 256, 0, stream>>>(node_x, combo, N);

    hist_kernel<<<NBLK_A, 256, 0, stream>>>(ei, hist, E, NB, chunk);
    scan1<<<nscan, 1024, 0, stream>>>(hist, hoff, bsums, nh);
    scan2<<<1, 128, 0, stream>>>(bsums, nscan);
    scan3<<<nscan, 1024, 0, stream>>>(hoff, bsums, nh);
    place_kernel<<<NBLK_A, 256, 0, stream>>>(ei, et, hoff, staged, E, NB, chunk);
    finalize_kernel<<<NB, 256, 0, stream>>>(staged, hoff, combo, edges1, edges2,
                                            base1, plen, E, N, NB);

    conv1_mfma<<<(N + 63) / 64, 256, 0, stream>>>(edges1, base1, B1f, root1t, combo, h1, N);
    gemm_Y<<<((N + 15) / 16 + 3) / 4, 256, 0, stream>>>(h1, B2f, b2, Rb, Y, N);
    conv2_gather<<<(N + 3) / 4, 256, 0, stream>>>(edges2, base1, plen, (const uint2*)Y,
                                                  (const uint2*)Rb, (uint2*)h2, N);
    pool_cls<<<G, 64, 0, stream>>>(h2, batch, cls_w, cls_b, out, N, G);
}